// Round 7
// baseline (169.610 us; speedup 1.0000x reference)
//
#include <hip/hip_runtime.h>
#include <hip/hip_bf16.h>

// ---------------------------------------------------------------------------
// Attention (B=2,N=2048,D=1024,H=16,DH=64) on gfx950 — full-fp16 pipeline.
//   1. prep: x -> fp16; Wq|Wk|Wv|Wo -> W^T fp16 (one fused kernel)
//   2. gemm<128,0>: q|k|v = x@W+b in ONE gemm; epilogue: rope (+log2e on q)
//      -> QK [2][B][H][N][64] fp16; v -> VT [B][H][64][N] fp16 (packed 8B)
//   3. attn: flash attn, 32x32x16 MFMA; wave = 32 q rows, KVBLK = 64.
//      Swapped QK^T (q lane-local), K/V LDS-staged (dbuf global_load_lds,
//      source-swizzled slot^=row&7), P relayout fully in registers via
//      shfl_xor(32) (no LDS), defer-max, exp2 softmax, bh-clustered grid.
//      NOTE: hi-pair lanes (lq, lq+32) hold disjoint key halves -> partial
//      sums MUST be combined via shfl_xor(32) (round-6 NaN bug).
//   4. gemm<64,2>: out = (ctx@Wo + bo) * query_mask, f32
// ---------------------------------------------------------------------------

typedef __fp16 fp16x2 __attribute__((ext_vector_type(2)));
typedef _Float16 f16x8 __attribute__((ext_vector_type(8)));
typedef float f32x4 __attribute__((ext_vector_type(4)));
typedef float f32x16 __attribute__((ext_vector_type(16)));

#define NEGBIG (-1.0e9f)

__device__ inline f32x4 mfma16(f16x8 a, f16x8 b, f32x4 c) {
  return __builtin_amdgcn_mfma_f32_16x16x32_f16(a, b, c, 0, 0, 0);
}
__device__ inline f32x16 mfma32(f16x8 a, f16x8 b, f32x16 c) {
  return __builtin_amdgcn_mfma_f32_32x32x16_f16(a, b, c, 0, 0, 0);
}

__device__ inline void gload16(const void* g, void* l) {
  __builtin_amdgcn_global_load_lds(
      (const __attribute__((address_space(1))) void*)g,
      (__attribute__((address_space(3))) void*)l, 16, 0, 0);
}

__device__ inline unsigned pk2u(float a, float b) {
  union { fp16x2 h; unsigned u; } x;
  x.h = __builtin_amdgcn_cvt_pkrtz(a, b);
  return x.u;
}

// -------------------------------- prep -------------------------------------
// z<4: W[z] [1024 k][1024 j] f32 -> wt + z*1M: [j][k] fp16 (transposed)
// z==4: x f32 -> fp16
__global__ __launch_bounds__(256) void prep_kernel(
    const float* __restrict__ x, const float* __restrict__ Wq,
    const float* __restrict__ Wk, const float* __restrict__ Wv,
    const float* __restrict__ Wo, _Float16* __restrict__ xh,
    _Float16* __restrict__ wt) {
  __shared__ float tile[32][33];
  const int z = blockIdx.z;
  const int tx = threadIdx.x, ty = threadIdx.y;
  if (z == 4) {
    const int bid = blockIdx.y * 32 + blockIdx.x;
    const int t = ty * 32 + tx;
#pragma unroll
    for (int i = 0; i < 4; ++i) {
      const int o = bid * 1024 + i * 256 + t;
      const float4 v = ((const float4*)x)[o];
      union { _Float16 h[4]; short4 s; } u;
      u.h[0] = (_Float16)v.x; u.h[1] = (_Float16)v.y;
      u.h[2] = (_Float16)v.z; u.h[3] = (_Float16)v.w;
      ((short4*)xh)[o] = u.s;
    }
    return;
  }
  const float* W = (z == 0) ? Wq : (z == 1) ? Wk : (z == 2) ? Wv : Wo;
  _Float16* dh = wt + (size_t)z * 1024 * 1024;
  const int j0 = blockIdx.x * 32, k0 = blockIdx.y * 32;
  for (int i = ty; i < 32; i += 8)
    tile[i][tx] = W[(size_t)(k0 + i) * 1024 + j0 + tx];
  __syncthreads();
  for (int i = ty; i < 32; i += 8)
    dh[(size_t)(j0 + i) * 1024 + k0 + tx] = (_Float16)tile[tx][i];
}

// -------------------------------- GEMM -------------------------------------
template <int TM, int EPI>
__global__ __launch_bounds__(256) void gemm_kernel(
    const _Float16* __restrict__ A, const _Float16* __restrict__ B,
    const float* __restrict__ bias0, const float* __restrict__ bias1,
    const float* __restrict__ bias2,
    const float* __restrict__ ropeC, const float* __restrict__ ropeS,
    const int* __restrict__ lens,
    _Float16* __restrict__ outQK, _Float16* __restrict__ outVT,
    float* __restrict__ outF) {
  constexpr int MI = TM / 32;
  __shared__ __align__(16) _Float16 smem[(TM + 128) * 32];
  const int t = threadIdx.x;
  const int w = t >> 6, lane = t & 63;
  const int wr = w >> 1, wc = w & 1;
  const int fr = lane & 15, fg = lane >> 4;
  const int mtile = blockIdx.x, ntile = blockIdx.y;

  const int srow = t >> 2;
  const int skel = (t & 3) << 3;
  const size_t aBase = (size_t)(mtile * TM + srow) * 1024 + skel;
  const size_t bBase = (size_t)(ntile * 128 + srow) * 1024 + skel;
  const int ldst = t * 8;
  _Float16* lA = &smem[0];
  _Float16* lB = &smem[TM * 32];

  f32x4 acc[MI][4];
#pragma unroll
  for (int i = 0; i < MI; ++i)
#pragma unroll
    for (int j = 0; j < 4; ++j) {
      acc[i][j][0] = 0.f; acc[i][j][1] = 0.f; acc[i][j][2] = 0.f; acc[i][j][3] = 0.f;
    }

  for (int k0 = 0; k0 < 1024; k0 += 32) {
    gload16(A + aBase + k0, lA + ldst);
    if constexpr (TM == 128) gload16(A + aBase + k0 + 64 * 1024, lA + ldst + 2048);
    gload16(B + bBase + k0, lB + ldst);
    gload16(B + bBase + k0 + 64 * 1024, lB + ldst + 2048);
    __syncthreads();

    f16x8 af[MI], bf[4];
#pragma unroll
    for (int mi = 0; mi < MI; ++mi)
      af[mi] = *(const f16x8*)&lA[(wr * (TM / 2) + mi * 16 + fr) * 32 + fg * 8];
#pragma unroll
    for (int ni = 0; ni < 4; ++ni)
      bf[ni] = *(const f16x8*)&lB[(wc * 64 + ni * 16 + fr) * 32 + fg * 8];
#pragma unroll
    for (int mi = 0; mi < MI; ++mi)
#pragma unroll
      for (int ni = 0; ni < 4; ++ni)
        acc[mi][ni] = mfma16(af[mi], bf[ni], acc[mi][ni]);
    __syncthreads();
  }

  const int rowbase = mtile * TM + wr * (TM / 2);
  const int colbase = ntile * 128 + wc * 64;

  if constexpr (EPI == 0) {
    const int which = colbase >> 10;  // 0=q 1=k 2=v (block-uniform)
    if (which < 2) {
      const float* bias = which ? bias1 : bias0;
#pragma unroll
      for (int ni = 0; ni < 4; ++ni) {
        const int gcol = colbase + ni * 16 + fr;
        const int jj = gcol & 1023;
        const int hh = jj >> 6, dd = jj & 63;
        const float bv = bias[jj];
#pragma unroll
        for (int mi = 0; mi < MI; ++mi) {
#pragma unroll
          for (int r = 0; r < 4; ++r) {
            const int grow = rowbase + mi * 16 + fg * 4 + r;
            const int b = grow >> 11, n = grow & 2047;
            float val = acc[mi][ni][r] + bv;
            float part = __shfl_xor(val, 1);
            const size_t ro = (size_t)(b * 2048 + n) * 1024 + jj;
            const float c = ropeC[ro], s = ropeS[ro];
            float rot = (fr & 1) ? (val * c + part * s) : (val * c - part * s);
            if (!which) rot *= 1.44269504f;  // log2e folded into q
            outQK[((size_t)((which * 2 + b) * 16 + hh) * 2048 + n) * 64 + dd] =
                (_Float16)rot;
          }
        }
      }
    } else {
#pragma unroll
      for (int ni = 0; ni < 4; ++ni) {
        const int gcol = colbase + ni * 16 + fr;
        const int jj = gcol & 1023;
        const int hh = jj >> 6, dd = jj & 63;
        const float bv = bias2[jj];
#pragma unroll
        for (int mi = 0; mi < MI; ++mi) {
          const int n0 = rowbase + mi * 16 + fg * 4;
          const int b = n0 >> 11, n = n0 & 2047;
          union { _Float16 h[4]; short4 s4; } u;
#pragma unroll
          for (int r = 0; r < 4; ++r) u.h[r] = (_Float16)(acc[mi][ni][r] + bv);
          *(short4*)(outVT + ((size_t)(b * 16 + hh) * 64 + dd) * 2048 + n) = u.s4;
        }
      }
    }
  } else {
    const int b = rowbase >> 11;
    const int len = lens[b];
#pragma unroll
    for (int ni = 0; ni < 4; ++ni) {
      const int gcol = colbase + ni * 16 + fr;
      const float bv = bias0[gcol];
#pragma unroll
      for (int mi = 0; mi < MI; ++mi) {
#pragma unroll
        for (int r = 0; r < 4; ++r) {
          const int m = rowbase + mi * 16 + fg * 4 + r;
          const int n = m & 2047;
          float val = acc[mi][ni][r] + bv;
          if (n >= len) val = 0.f;
          outF[(size_t)m * 1024 + gcol] = val;
        }
      }
    }
  }
}

// ------------------------------ attention ----------------------------------
// 1024 blocks (bh-clustered for XCD L2), 2 waves x 32 q rows. KVBLK = 64.
// mfma 32x32x16: S^T = K·Q^T -> col = lane&31 = q (lane-local softmax),
// row = (r&3)+8*(r>>2)+4*(lane>>5) = key. P->A-frag relayout fully in
// registers via one shfl_xor(32) exchange per fragment pair.
// LDS: 2 x { K[64][64] 8KB | V[64][64] 8KB } = 32 KiB, no P buffer.
__global__ __launch_bounds__(128, 2) void attn_kernel(
    const _Float16* __restrict__ qk, const _Float16* __restrict__ vt,
    const int* __restrict__ lens, _Float16* __restrict__ ctx) {
  __shared__ __align__(16) char lds[32768];
  const int t = threadIdx.x;
  const int w = t >> 6, lane = t & 63;
  const int lq = lane & 31, hi = lane >> 5;
  const int fid = blockIdx.x;
  const int qtile = (fid >> 3) & 31;
  const int bh = (fid & 7) + ((fid >> 8) << 3);  // cluster same-bh on one XCD
  const int b = bh >> 4, h = bh & 15;
  const int len = lens[b];
  const int q0w = qtile * 64 + w * 32;
  const size_t qoff = (size_t)(b * 16 + h) * 2048 * 64;
  const size_t koff = (size_t)((2 + b) * 16 + h) * 2048 * 64;
  const size_t voff = (size_t)(b * 16 + h) * 64 * 2048;

  // Q B-frags: lane lq = q row, k = ks*16 + hi*8 + j
  f16x8 qf[4];
#pragma unroll
  for (int ks = 0; ks < 4; ++ks)
    qf[ks] = *(const f16x8*)(qk + qoff + (size_t)(q0w + lq) * 64 + ks * 16 + hi * 8);

  // staging: linear LDS dest (base + t*16), source pre-swizzled slot^=row&7
  const int srow = t >> 3;
  const int sslot = (t & 7) ^ (srow & 7);
  const size_t kg = koff + (size_t)srow * 64 + sslot * 8;
  const size_t vg = voff + (size_t)srow * 2048 + sslot * 8;

  f32x16 o0, o1;
#pragma unroll
  for (int i = 0; i < 16; ++i) { o0[i] = 0.f; o1[i] = 0.f; }
  float mrun = -1e30f, lsum = 0.f;  // per-lane, q = lq (replicated on hi pair)

#define STAGE(bi, k0_) do { \
    char* dst = lds + (bi) * 16384 + t * 16; \
    const _Float16* ks_ = qk + kg + (size_t)(k0_) * 64; \
    const _Float16* vs_ = vt + vg + (k0_); \
    gload16(ks_, dst); gload16(ks_ + 1024, dst + 2048); \
    gload16(ks_ + 2048, dst + 4096); gload16(ks_ + 3072, dst + 6144); \
    gload16(vs_, dst + 8192); gload16(vs_ + 32768, dst + 10240); \
    gload16(vs_ + 65536, dst + 12288); gload16(vs_ + 98304, dst + 14336); \
  } while (0)

  const int nkb = (len + 63) >> 6;
  STAGE(0, 0);

  for (int kb = 0; kb < nkb; ++kb) {
    const int cur = kb & 1;
    if (kb + 1 < nkb) {
      STAGE(cur ^ 1, (kb + 1) * 64);
      asm volatile("s_waitcnt vmcnt(8)" ::: "memory");
    } else {
      asm volatile("s_waitcnt vmcnt(0)" ::: "memory");
    }
    __builtin_amdgcn_s_barrier();

    const char* Kb = lds + cur * 16384;
    const char* Vb = Kb + 8192;
    const int rsw = (lq & 7) << 4;

    f32x16 s0, s1;
#pragma unroll
    for (int i = 0; i < 16; ++i) { s0[i] = 0.f; s1[i] = 0.f; }
    __builtin_amdgcn_s_setprio(1);
#pragma unroll
    for (int ks = 0; ks < 4; ++ks) {
      const int col = ks * 32 + hi * 16;
      const f16x8 k0f = *(const f16x8*)(Kb + lq * 128 + (col ^ rsw));
      const f16x8 k1f = *(const f16x8*)(Kb + (32 + lq) * 128 + (col ^ rsw));
      s0 = mfma32(k0f, qf[ks], s0);
      s1 = mfma32(k1f, qf[ks], s1);
    }
    __builtin_amdgcn_s_setprio(0);

    if (kb == nkb - 1 && (len & 63)) {
#pragma unroll
      for (int r = 0; r < 16; ++r) {
        const int key = kb * 64 + (r & 3) + ((r >> 2) << 3) + hi * 4;
        if (key >= len) s0[r] = NEGBIG;
        if (key + 32 >= len) s1[r] = NEGBIG;
      }
    }

    // --- online softmax (log2 domain), q lane-local ---
    float mx = s0[0];
#pragma unroll
    for (int r = 1; r < 16; ++r) mx = fmaxf(mx, s0[r]);
#pragma unroll
    for (int r = 0; r < 16; ++r) mx = fmaxf(mx, s1[r]);
    mx = fmaxf(mx, __shfl_xor(mx, 32));

    if (!__all(mx <= mrun + 8.f)) {  // defer-max
      const float mnew = fmaxf(mrun, mx);
      const float scq = exp2f(mrun - mnew);
      mrun = mnew;
      lsum *= scq;
      float sc[16];
#pragma unroll
      for (int r = 0; r < 16; ++r)
        sc[r] = __shfl(scq, (r & 3) + ((r >> 2) << 3) + hi * 4);
#pragma unroll
      for (int r = 0; r < 16; ++r) { o0[r] *= sc[r]; o1[r] *= sc[r]; }
    }

    // p = exp2(s - m); pack pairs (consecutive keys) to fp16 words; sum
    unsigned W[16];
    float ps = 0.f;
#pragma unroll
    for (int u = 0; u < 4; ++u) {
      const float p0 = exp2f(s0[4 * u + 0] - mrun);
      const float p1 = exp2f(s0[4 * u + 1] - mrun);
      const float p2 = exp2f(s0[4 * u + 2] - mrun);
      const float p3 = exp2f(s0[4 * u + 3] - mrun);
      ps += (p0 + p1) + (p2 + p3);
      W[2 * u] = pk2u(p0, p1);
      W[2 * u + 1] = pk2u(p2, p3);
    }
#pragma unroll
    for (int u = 0; u < 4; ++u) {
      const float p0 = exp2f(s1[4 * u + 0] - mrun);
      const float p1 = exp2f(s1[4 * u + 1] - mrun);
      const float p2 = exp2f(s1[4 * u + 2] - mrun);
      const float p3 = exp2f(s1[4 * u + 3] - mrun);
      ps += (p0 + p1) + (p2 + p3);
      W[8 + 2 * u] = pk2u(p0, p1);
      W[8 + 2 * u + 1] = pk2u(p2, p3);
    }
    ps += __shfl_xor(ps, 32);  // combine disjoint key halves of the hi pair
    lsum += ps;

    // --- PV: assemble P A-frags in registers (lane<->lane^32 exchange) ---
    __builtin_amdgcn_s_setprio(1);
#pragma unroll
    for (int ks = 0; ks < 4; ++ks) {
      const unsigned w0 = W[4 * ks + 0], w1 = W[4 * ks + 1];
      const unsigned w2 = W[4 * ks + 2], w3 = W[4 * ks + 3];
      const unsigned sendA = hi ? w0 : w2;
      const unsigned sendB = hi ? w1 : w3;
      const unsigned recvA = __shfl_xor(sendA, 32);
      const unsigned recvB = __shfl_xor(sendB, 32);
      union { unsigned u[4]; f16x8 v; } af;
      af.u[0] = hi ? recvA : w0;
      af.u[1] = hi ? recvB : w1;
      af.u[2] = hi ? w2 : recvA;
      af.u[3] = hi ? w3 : recvB;
      const int col = ks * 32 + hi * 16;
      const f16x8 v0f = *(const f16x8*)(Vb + lq * 128 + (col ^ rsw));
      const f16x8 v1f = *(const f16x8*)(Vb + (32 + lq) * 128 + (col ^ rsw));
      o0 = mfma32(af.v, v0f, o0);
      o1 = mfma32(af.v, v1f, o1);
    }
    __builtin_amdgcn_s_setprio(0);

    asm volatile("" ::: "memory");
    __builtin_amdgcn_s_barrier();
  }
#undef STAGE

  const float li = 1.f / lsum;
#pragma unroll
  for (int r = 0; r < 16; ++r) {
    const int qr = (r & 3) + ((r >> 2) << 3) + hi * 4;
    const float lr = __shfl(li, qr);
    const int n = q0w + qr;
    _Float16* dst = ctx + (size_t)(b * 2048 + n) * 1024 + h * 64;
    dst[lq] = (_Float16)(o0[r] * lr);
    dst[32 + lq] = (_Float16)(o1[r] * lr);
  }
}

// ------------------------------ launcher -----------------------------------

extern "C" void kernel_launch(void* const* d_in, const int* in_sizes, int n_in,
                              void* d_out, int out_size, void* d_ws, size_t ws_size,
                              hipStream_t stream) {
  const float* x = (const float*)d_in[0];
  const float* rc = (const float*)d_in[1];
  const float* rs = (const float*)d_in[2];
  const int* lens = (const int*)d_in[3];
  const float* Wq = (const float*)d_in[4];
  const float* bq = (const float*)d_in[5];
  const float* Wk = (const float*)d_in[6];
  const float* bk = (const float*)d_in[7];
  const float* Wv = (const float*)d_in[8];
  const float* bv = (const float*)d_in[9];
  const float* Wo = (const float*)d_in[10];
  const float* bo = (const float*)d_in[11];
  float* out = (float*)d_out;

  char* ws = (char*)d_ws;
  const size_t MB = 1024 * 1024;
  _Float16* XH = (_Float16*)(ws + 0);        // [4096][1024]          8 MB
  _Float16* WT = (_Float16*)(ws + 8 * MB);   // [4][1024 j][1024 k]   8 MB
  _Float16* QK = (_Float16*)(ws + 16 * MB);  // [2][2][16][2048][64] 16 MB
  _Float16* VT = (_Float16*)(ws + 32 * MB);  // [2][16][64][2048]     8 MB
  _Float16* CTX = (_Float16*)(ws + 40 * MB); // [4096][1024]          8 MB

  prep_kernel<<<dim3(32, 32, 5), dim3(32, 8), 0, stream>>>(x, Wq, Wk, Wv, Wo,
                                                           XH, WT);
  gemm_kernel<128, 0><<<dim3(32, 24), 256, 0, stream>>>(
      XH, WT, bq, bk, bv, rc, rs, nullptr, QK, VT, nullptr);
  attn_kernel<<<1024, 128, 0, stream>>>(QK, VT, lens, CTX);
  gemm_kernel<64, 2><<<dim3(64, 8), 256, 0, stream>>>(
      CTX, WT + (size_t)3 * 1024 * 1024, bo, nullptr, nullptr, nullptr,
      nullptr, lens, nullptr, nullptr, out);
}

// Round 8
// 161.229 us; speedup vs baseline: 1.0520x; 1.0520x over previous
//
#include <hip/hip_runtime.h>
#include <hip/hip_bf16.h>

// ---------------------------------------------------------------------------
// Attention (B=2,N=2048,D=1024,H=16,DH=64) on gfx950 — full-fp16 pipeline.
//   1. prep: x -> fp16; Wq|Wk|Wv|Wo -> W^T fp16 (one fused kernel)
//   2. gemm<128,0>: q|k|v = x@W+b in ONE gemm; epilogue: rope (+log2e on q)
//      -> QK [2][B][H][N][64] fp16; v -> VT [B][H][64][N] fp16 (packed 8B)
//   3. attn: flash attn, 32x32x16 MFMA, KVBLK=32, 2-WAY KEY SPLIT
//      (flash-decoding): 2048 blocks x 2 waves = 4096 waves (2x round-7).
//      Swapped QK^T (q lane-local), K/V LDS (16KB dbuf, global_load_lds,
//      XOR-swizzled via pre-swizzled source), in-register P relayout via
//      shfl_xor(32), defer-max, exp2 softmax. Writes unnormalized partials
//      po (f32) + (m,l) per row.
//   4. combine: merge 2 segments -> ctx fp16.
//   5. gemm<64,2>: out = (ctx@Wo + bo) * query_mask, f32
// ---------------------------------------------------------------------------

typedef __fp16 fp16x2 __attribute__((ext_vector_type(2)));
typedef _Float16 f16x8 __attribute__((ext_vector_type(8)));
typedef float f32x4 __attribute__((ext_vector_type(4)));
typedef float f32x16 __attribute__((ext_vector_type(16)));

#define NEGBIG (-1.0e9f)

__device__ inline f32x4 mfma16(f16x8 a, f16x8 b, f32x4 c) {
  return __builtin_amdgcn_mfma_f32_16x16x32_f16(a, b, c, 0, 0, 0);
}
__device__ inline f32x16 mfma32(f16x8 a, f16x8 b, f32x16 c) {
  return __builtin_amdgcn_mfma_f32_32x32x16_f16(a, b, c, 0, 0, 0);
}

__device__ inline void gload16(const void* g, void* l) {
  __builtin_amdgcn_global_load_lds(
      (const __attribute__((address_space(1))) void*)g,
      (__attribute__((address_space(3))) void*)l, 16, 0, 0);
}

__device__ inline unsigned pk2u(float a, float b) {
  union { fp16x2 h; unsigned u; } x;
  x.h = __builtin_amdgcn_cvt_pkrtz(a, b);
  return x.u;
}

// -------------------------------- prep -------------------------------------
__global__ __launch_bounds__(256) void prep_kernel(
    const float* __restrict__ x, const float* __restrict__ Wq,
    const float* __restrict__ Wk, const float* __restrict__ Wv,
    const float* __restrict__ Wo, _Float16* __restrict__ xh,
    _Float16* __restrict__ wt) {
  __shared__ float tile[32][33];
  const int z = blockIdx.z;
  const int tx = threadIdx.x, ty = threadIdx.y;
  if (z == 4) {
    const int bid = blockIdx.y * 32 + blockIdx.x;
    const int t = ty * 32 + tx;
#pragma unroll
    for (int i = 0; i < 4; ++i) {
      const int o = bid * 1024 + i * 256 + t;
      const float4 v = ((const float4*)x)[o];
      union { _Float16 h[4]; short4 s; } u;
      u.h[0] = (_Float16)v.x; u.h[1] = (_Float16)v.y;
      u.h[2] = (_Float16)v.z; u.h[3] = (_Float16)v.w;
      ((short4*)xh)[o] = u.s;
    }
    return;
  }
  const float* W = (z == 0) ? Wq : (z == 1) ? Wk : (z == 2) ? Wv : Wo;
  _Float16* dh = wt + (size_t)z * 1024 * 1024;
  const int j0 = blockIdx.x * 32, k0 = blockIdx.y * 32;
  for (int i = ty; i < 32; i += 8)
    tile[i][tx] = W[(size_t)(k0 + i) * 1024 + j0 + tx];
  __syncthreads();
  for (int i = ty; i < 32; i += 8)
    dh[(size_t)(j0 + i) * 1024 + k0 + tx] = (_Float16)tile[tx][i];
}

// -------------------------------- GEMM -------------------------------------
template <int TM, int EPI>
__global__ __launch_bounds__(256) void gemm_kernel(
    const _Float16* __restrict__ A, const _Float16* __restrict__ B,
    const float* __restrict__ bias0, const float* __restrict__ bias1,
    const float* __restrict__ bias2,
    const float* __restrict__ ropeC, const float* __restrict__ ropeS,
    const int* __restrict__ lens,
    _Float16* __restrict__ outQK, _Float16* __restrict__ outVT,
    float* __restrict__ outF) {
  constexpr int MI = TM / 32;
  __shared__ __align__(16) _Float16 smem[(TM + 128) * 32];
  const int t = threadIdx.x;
  const int w = t >> 6, lane = t & 63;
  const int wr = w >> 1, wc = w & 1;
  const int fr = lane & 15, fg = lane >> 4;
  const int mtile = blockIdx.x, ntile = blockIdx.y;

  const int srow = t >> 2;
  const int skel = (t & 3) << 3;
  const size_t aBase = (size_t)(mtile * TM + srow) * 1024 + skel;
  const size_t bBase = (size_t)(ntile * 128 + srow) * 1024 + skel;
  const int ldst = t * 8;
  _Float16* lA = &smem[0];
  _Float16* lB = &smem[TM * 32];

  f32x4 acc[MI][4];
#pragma unroll
  for (int i = 0; i < MI; ++i)
#pragma unroll
    for (int j = 0; j < 4; ++j) {
      acc[i][j][0] = 0.f; acc[i][j][1] = 0.f; acc[i][j][2] = 0.f; acc[i][j][3] = 0.f;
    }

  for (int k0 = 0; k0 < 1024; k0 += 32) {
    gload16(A + aBase + k0, lA + ldst);
    if constexpr (TM == 128) gload16(A + aBase + k0 + 64 * 1024, lA + ldst + 2048);
    gload16(B + bBase + k0, lB + ldst);
    gload16(B + bBase + k0 + 64 * 1024, lB + ldst + 2048);
    __syncthreads();

    f16x8 af[MI], bf[4];
#pragma unroll
    for (int mi = 0; mi < MI; ++mi)
      af[mi] = *(const f16x8*)&lA[(wr * (TM / 2) + mi * 16 + fr) * 32 + fg * 8];
#pragma unroll
    for (int ni = 0; ni < 4; ++ni)
      bf[ni] = *(const f16x8*)&lB[(wc * 64 + ni * 16 + fr) * 32 + fg * 8];
#pragma unroll
    for (int mi = 0; mi < MI; ++mi)
#pragma unroll
      for (int ni = 0; ni < 4; ++ni)
        acc[mi][ni] = mfma16(af[mi], bf[ni], acc[mi][ni]);
    __syncthreads();
  }

  const int rowbase = mtile * TM + wr * (TM / 2);
  const int colbase = ntile * 128 + wc * 64;

  if constexpr (EPI == 0) {
    const int which = colbase >> 10;  // 0=q 1=k 2=v (block-uniform)
    if (which < 2) {
      const float* bias = which ? bias1 : bias0;
#pragma unroll
      for (int ni = 0; ni < 4; ++ni) {
        const int gcol = colbase + ni * 16 + fr;
        const int jj = gcol & 1023;
        const int hh = jj >> 6, dd = jj & 63;
        const float bv = bias[jj];
#pragma unroll
        for (int mi = 0; mi < MI; ++mi) {
#pragma unroll
          for (int r = 0; r < 4; ++r) {
            const int grow = rowbase + mi * 16 + fg * 4 + r;
            const int b = grow >> 11, n = grow & 2047;
            float val = acc[mi][ni][r] + bv;
            float part = __shfl_xor(val, 1);
            const size_t ro = (size_t)(b * 2048 + n) * 1024 + jj;
            const float c = ropeC[ro], s = ropeS[ro];
            float rot = (fr & 1) ? (val * c + part * s) : (val * c - part * s);
            if (!which) rot *= 1.44269504f;  // log2e folded into q
            outQK[((size_t)((which * 2 + b) * 16 + hh) * 2048 + n) * 64 + dd] =
                (_Float16)rot;
          }
        }
      }
    } else {
#pragma unroll
      for (int ni = 0; ni < 4; ++ni) {
        const int gcol = colbase + ni * 16 + fr;
        const int jj = gcol & 1023;
        const int hh = jj >> 6, dd = jj & 63;
        const float bv = bias2[jj];
#pragma unroll
        for (int mi = 0; mi < MI; ++mi) {
          const int n0 = rowbase + mi * 16 + fg * 4;
          const int b = n0 >> 11, n = n0 & 2047;
          union { _Float16 h[4]; short4 s4; } u;
#pragma unroll
          for (int r = 0; r < 4; ++r) u.h[r] = (_Float16)(acc[mi][ni][r] + bv);
          *(short4*)(outVT + ((size_t)(b * 16 + hh) * 64 + dd) * 2048 + n) = u.s4;
        }
      }
    }
  } else {
    const int b = rowbase >> 11;
    const int len = lens[b];
#pragma unroll
    for (int ni = 0; ni < 4; ++ni) {
      const int gcol = colbase + ni * 16 + fr;
      const float bv = bias0[gcol];
#pragma unroll
      for (int mi = 0; mi < MI; ++mi) {
#pragma unroll
        for (int r = 0; r < 4; ++r) {
          const int m = rowbase + mi * 16 + fg * 4 + r;
          const int n = m & 2047;
          float val = acc[mi][ni][r] + bv;
          if (n >= len) val = 0.f;
          outF[(size_t)m * 1024 + gcol] = val;
        }
      }
    }
  }
}

// ------------------------------ attention ----------------------------------
// 2048 blocks (32 qtile x 32 bh x 2 seg, XCD-clustered by (bh,seg)), 2 waves
// x 32 q rows, KVBLK=32. S^T = mfma32(K,Q): col=lane&31=q (lane-local),
// row=(r&3)+8*(r>>2)+4*hi = key. P->PV A-frag in registers via shfl_xor(32).
// Key-split: seg 0 = tiles [0,nk0), seg 1 = [nk0,nkb). Unnormalized partial
// o + (m,l) per q row -> po/ml. LDS 2 x { K[32][64] 4KB | V 4KB } = 16 KiB.
__global__ __launch_bounds__(128, 4) void attn_kernel(
    const _Float16* __restrict__ qk, const _Float16* __restrict__ vt,
    const int* __restrict__ lens, float* __restrict__ po,
    float2* __restrict__ ml) {
  __shared__ __align__(16) char lds[16384];
  const int t = threadIdx.x;
  const int w = t >> 6, lane = t & 63;
  const int lq = lane & 31, hi = lane >> 5;
  const int gid = blockIdx.x;
  const int bh_seg = (gid & 7) + ((gid >> 8) << 3);  // cluster on one XCD
  const int qtile = (gid >> 3) & 31;
  const int bh = bh_seg >> 1, seg = bh_seg & 1;
  const int b = bh >> 4, h = bh & 15;
  const int len = lens[b];
  const int q0w = qtile * 64 + w * 32;
  const size_t qoff = (size_t)(b * 16 + h) * 2048 * 64;
  const size_t koff = (size_t)((2 + b) * 16 + h) * 2048 * 64;
  const size_t voff = (size_t)(b * 16 + h) * 64 * 2048;

  // Q B-frags: lane lq = q row, k = ks*16 + hi*8 + j
  f16x8 qf[4];
#pragma unroll
  for (int ks = 0; ks < 4; ++ks)
    qf[ks] = *(const f16x8*)(qk + qoff + (size_t)(q0w + lq) * 64 + ks * 16 + hi * 8);

  // staging: linear LDS dest, pre-swizzled source slot ss = (t&7)^(srow&7).
  // K tile [32 keys][64 d]; V tile [32 rows][128B]: row r = d(r) bytes 0..63,
  // d(r)+32 bytes 64..127 (slot>>2 selects the d-half).
  const int srow = t >> 3;                    // 0..15 (two issues: +16)
  const int ss = (t & 7) ^ (srow & 7);
  const size_t kg = koff + (size_t)srow * 64 + ss * 8;   // + key0*64
  const int vd = srow + ((ss >> 2) << 5);
  const size_t vg1 = voff + (size_t)vd * 2048 + (ss & 3) * 8;        // + key0
  const size_t vg2 = voff + (size_t)(vd + 16) * 2048 + (ss & 3) * 8;

  f32x16 o0, o1;
#pragma unroll
  for (int i = 0; i < 16; ++i) { o0[i] = 0.f; o1[i] = 0.f; }
  float mrun = -1e30f, lsum = 0.f;  // per-lane, q = lq (replicated on hi pair)

#define STAGE(bi, kb_) do { \
    char* dst = lds + (bi) * 8192 + t * 16; \
    const size_t k064 = (size_t)(kb_) * 2048; /* kb*32*64 */ \
    gload16(qk + kg + k064, dst); \
    gload16(qk + kg + k064 + 1024, dst + 2048); \
    gload16(vt + vg1 + (kb_) * 32, dst + 4096); \
    gload16(vt + vg2 + (kb_) * 32, dst + 6144); \
  } while (0)

  const int nkb = (len + 31) >> 5;
  const int nk0 = (nkb + 1) >> 1;
  const int tb0 = seg ? nk0 : 0;
  const int tb1 = seg ? nkb : nk0;

  STAGE(0, tb0);

  for (int kb = tb0; kb < tb1; ++kb) {
    const int cur = (kb - tb0) & 1;
    if (kb + 1 < tb1) {
      STAGE(cur ^ 1, kb + 1);
      asm volatile("s_waitcnt vmcnt(4)" ::: "memory");
    } else {
      asm volatile("s_waitcnt vmcnt(0)" ::: "memory");
    }
    __builtin_amdgcn_s_barrier();

    const char* Kb = lds + cur * 8192;
    const char* Vb = Kb + 4096;
    const int rsw = (lq & 7) << 4;

    f32x16 s0;
#pragma unroll
    for (int i = 0; i < 16; ++i) s0[i] = 0.f;
    __builtin_amdgcn_s_setprio(1);
#pragma unroll
    for (int ks = 0; ks < 4; ++ks) {
      const f16x8 kf = *(const f16x8*)(Kb + lq * 128 + ((ks * 32 + hi * 16) ^ rsw));
      s0 = mfma32(kf, qf[ks], s0);
    }
    __builtin_amdgcn_s_setprio(0);

    if (kb == nkb - 1 && (len & 31)) {
#pragma unroll
      for (int r = 0; r < 16; ++r) {
        const int key = kb * 32 + (r & 3) + ((r >> 2) << 3) + hi * 4;
        if (key >= len) s0[r] = NEGBIG;
      }
    }

    // --- online softmax (log2 domain), q lane-local ---
    float mx = s0[0];
#pragma unroll
    for (int r = 1; r < 16; ++r) mx = fmaxf(mx, s0[r]);
    mx = fmaxf(mx, __shfl_xor(mx, 32));

    if (!__all(mx <= mrun + 8.f)) {  // defer-max
      const float mnew = fmaxf(mrun, mx);
      const float scq = exp2f(mrun - mnew);
      mrun = mnew;
      lsum *= scq;
      float sc[16];
#pragma unroll
      for (int r = 0; r < 16; ++r)
        sc[r] = __shfl(scq, (r & 3) + ((r >> 2) << 3) + hi * 4);
#pragma unroll
      for (int r = 0; r < 16; ++r) { o0[r] *= sc[r]; o1[r] *= sc[r]; }
    }

    // p = exp2(s - m); pack pairs (consecutive keys) to fp16 words; sum.
    // W[2u]   = (p[4u],   p[4u+1]) = keys {8u,   8u+1} + 4*hi
    // W[2u+1] = (p[4u+2], p[4u+3]) = keys {8u+2, 8u+3} + 4*hi
    unsigned W[8];
    float ps = 0.f;
#pragma unroll
    for (int u = 0; u < 4; ++u) {
      const float p0 = exp2f(s0[4 * u + 0] - mrun);
      const float p1 = exp2f(s0[4 * u + 1] - mrun);
      const float p2 = exp2f(s0[4 * u + 2] - mrun);
      const float p3 = exp2f(s0[4 * u + 3] - mrun);
      ps += (p0 + p1) + (p2 + p3);
      W[2 * u] = pk2u(p0, p1);
      W[2 * u + 1] = pk2u(p2, p3);
    }
    ps += __shfl_xor(ps, 32);  // combine disjoint key halves of the hi pair
    lsum += ps;

    // --- PV: assemble P A-frags in registers (lane<->lane^32 exchange) ---
    __builtin_amdgcn_s_setprio(1);
#pragma unroll
    for (int ks = 0; ks < 2; ++ks) {
      const unsigned w0 = W[4 * ks + 0], w1 = W[4 * ks + 1];
      const unsigned w2 = W[4 * ks + 2], w3 = W[4 * ks + 3];
      const unsigned sendA = hi ? w0 : w2;
      const unsigned sendB = hi ? w1 : w3;
      const unsigned recvA = __shfl_xor(sendA, 32);
      const unsigned recvB = __shfl_xor(sendB, 32);
      union { unsigned u[4]; f16x8 v; } af;
      af.u[0] = hi ? recvA : w0;
      af.u[1] = hi ? recvB : w1;
      af.u[2] = hi ? w2 : recvA;
      af.u[3] = hi ? w3 : recvB;
      const int g0 = ks * 2 + hi;       // V slot, d-half 0
      const f16x8 v0f = *(const f16x8*)(Vb + lq * 128 + ((g0 << 4) ^ rsw));
      const f16x8 v1f = *(const f16x8*)(Vb + lq * 128 + (((g0 + 4) << 4) ^ rsw));
      o0 = mfma32(af.v, v0f, o0);
      o1 = mfma32(af.v, v1f, o1);
    }
    __builtin_amdgcn_s_setprio(0);

    asm volatile("" ::: "memory");
    __builtin_amdgcn_s_barrier();
  }
#undef STAGE

  // epilogue: unnormalized partials (row = bh*2048 + n)
  const size_t rowbase = (size_t)bh * 2048 + q0w;
  float* pod = po + ((size_t)seg * 65536 + rowbase) * 64;
#pragma unroll
  for (int r = 0; r < 16; ++r) {
    const int qr = (r & 3) + ((r >> 2) << 3) + hi * 4;
    pod[qr * 64 + lq] = o0[r];
    pod[qr * 64 + 32 + lq] = o1[r];
  }
  if (hi == 0) {
    float2 v; v.x = mrun; v.y = lsum;
    ml[(size_t)seg * 65536 + rowbase + lq] = v;
  }
}

// ------------------------------ combine ------------------------------------
// Merge 2 key-segments: o = sum po_s * exp2(m_s - m), l likewise; ctx = o/l.
__global__ __launch_bounds__(256) void combine_kernel(
    const float* __restrict__ po, const float2* __restrict__ ml,
    _Float16* __restrict__ ctx) {
  const int tid = blockIdx.x * 256 + threadIdx.x;  // 262144
  const int row = tid >> 2, dg = tid & 3;
  const float2 a = ml[row], c = ml[65536 + row];
  const float m = fmaxf(a.x, c.x);
  const float e0 = exp2f(a.x - m), e1 = exp2f(c.x - m);
  const float inv = 1.f / (a.y * e0 + c.y * e1);
  const float f0 = e0 * inv, f1 = e1 * inv;
  const float4* p0 = (const float4*)(po + (size_t)row * 64 + dg * 16);
  const float4* p1 = (const float4*)(po + (size_t)(65536 + row) * 64 + dg * 16);
  const int bh = row >> 11, n = row & 2047, b = bh >> 4, h = bh & 15;
  _Float16* dst = ctx + ((size_t)(b * 2048 + n) * 1024 + h * 64 + dg * 16);
#pragma unroll
  for (int i = 0; i < 4; ++i) {
    const float4 v0 = p0[i], v1 = p1[i];
    union { _Float16 h[4]; short4 s4; } u;
    u.h[0] = (_Float16)(v0.x * f0 + v1.x * f1);
    u.h[1] = (_Float16)(v0.y * f0 + v1.y * f1);
    u.h[2] = (_Float16)(v0.z * f0 + v1.z * f1);
    u.h[3] = (_Float16)(v0.w * f0 + v1.w * f1);
    *(short4*)(dst + i * 4) = u.s4;
  }
}

// ------------------------------ launcher -----------------------------------

extern "C" void kernel_launch(void* const* d_in, const int* in_sizes, int n_in,
                              void* d_out, int out_size, void* d_ws, size_t ws_size,
                              hipStream_t stream) {
  const float* x = (const float*)d_in[0];
  const float* rc = (const float*)d_in[1];
  const float* rs = (const float*)d_in[2];
  const int* lens = (const int*)d_in[3];
  const float* Wq = (const float*)d_in[4];
  const float* bq = (const float*)d_in[5];
  const float* Wk = (const float*)d_in[6];
  const float* bk = (const float*)d_in[7];
  const float* Wv = (const float*)d_in[8];
  const float* bv = (const float*)d_in[9];
  const float* Wo = (const float*)d_in[10];
  const float* bo = (const float*)d_in[11];
  float* out = (float*)d_out;

  char* ws = (char*)d_ws;
  const size_t MB = 1024 * 1024;
  _Float16* XH = (_Float16*)(ws + 0);        // [4096][1024]          8 MB
  _Float16* WT = (_Float16*)(ws + 8 * MB);   // [4][1024 j][1024 k]   8 MB
  _Float16* QK = (_Float16*)(ws + 16 * MB);  // [2][2][16][2048][64] 16 MB
  _Float16* VT = (_Float16*)(ws + 32 * MB);  // [2][16][64][2048]     8 MB
  _Float16* CTX = (_Float16*)(ws + 40 * MB); // [4096][1024]          8 MB
  float* PO = (float*)(ws + 48 * MB);        // [2][65536][64] f32   32 MB
  float2* ML = (float2*)(ws + 81 * MB);      // [2][65536] float2     1 MB

  prep_kernel<<<dim3(32, 32, 5), dim3(32, 8), 0, stream>>>(x, Wq, Wk, Wv, Wo,
                                                           XH, WT);
  gemm_kernel<128, 0><<<dim3(32, 24), 256, 0, stream>>>(
      XH, WT, bq, bk, bv, rc, rs, nullptr, QK, VT, nullptr);
  attn_kernel<<<2048, 128, 0, stream>>>(QK, VT, lens, PO, ML);
  combine_kernel<<<1024, 256, 0, stream>>>(PO, ML, CTX);
  gemm_kernel<64, 2><<<dim3(64, 8), 256, 0, stream>>>(
      CTX, WT + (size_t)3 * 1024 * 1024, bo, nullptr, nullptr, nullptr,
      nullptr, lens, nullptr, nullptr, out);
}